// Round 10
// baseline (1103.604 us; speedup 1.0000x reference)
//
#include <hip/hip_runtime.h>
#include <utility>

using u16 = unsigned short;
using u32 = unsigned int;

typedef float  f32x16 __attribute__((ext_vector_type(16)));
typedef __bf16 bf16x8 __attribute__((ext_vector_type(8)));

#define DI __device__ __forceinline__

// ------------------------------------------------------------------
// Monomial basis under the +8 rotation group (for 32x32x16 MFMA).
// Monomials over x[0..15]: cubic multisets (816), quadratic (136),
// linear (16).  Group action: index rotation by +8 mod 16 (h=0,1).
// Cubic orbits all have size 2 -> 408 reps; quad: 64 size-2 orbits +
// 8 fixed -> 72 reps; linear -> 8 reps.  Total 488 = 61 chunks * 8,
// ZERO padding.
// Feature slot f = chunk*16 + h*8 + j  <->  rep r = chunk*8 + j,
// monomial = rot_{8h}(rep[r]).  Lane half h = lane>>5 holds x rotated
// by 8h at the address level, so all lanes run identical
// compile-time-indexed code.
// Fixed quads ({a,a+8}): h=1 slot's monomial already claimed by the
// h=0 slot -> slotmono.t stays 0 -> S row written as 0 (no dup count).
// ------------------------------------------------------------------
struct RepT { unsigned char a, b, c, t; };   // t: 3=cubic 2=quad 1=linear 0=null
struct Tables8 {
  RepT rep[488];        // compile-time rep list for feature templates
  RepT slotmono[976];   // per feature-slot: SORTED monomial (for prep gather)
  int n3, n2, n1;
};

constexpr int csort3key(int w, int x, int i) {
  int a = w, b = x, c = i, t = 0;
  if (a > b) { t = a; a = b; b = t; }
  if (b > c) { t = b; b = c; c = t; }
  if (a > b) { t = a; a = b; b = t; }
  return (a << 8) | (b << 4) | c;
}

constexpr Tables8 build_tables8() {
  Tables8 T = {};
  bool used3[4096] = {};
  bool used2[256] = {};
  int nr = 0;
  // cubic multisets a<=b<=c, canonical = lex-min of the 2 rotations
  for (int a = 0; a < 16; a++) for (int b = a; b < 16; b++) for (int c = b; c < 16; c++) {
    const int key  = (a << 8) | (b << 4) | c;
    const int key2 = csort3key((a + 8) & 15, (b + 8) & 15, (c + 8) & 15);
    if (key2 < key) continue;
    for (int h = 0; h < 2; h++) {
      const int kk = h ? key2 : key;
      if (!used3[kk]) {
        used3[kk] = true;
        const int f = (nr >> 3) * 16 + h * 8 + (nr & 7);
        T.slotmono[f].a = (unsigned char)(kk >> 8);
        T.slotmono[f].b = (unsigned char)((kk >> 4) & 15);
        T.slotmono[f].c = (unsigned char)(kk & 15);
        T.slotmono[f].t = 3;
      }
    }
    T.rep[nr].a = (unsigned char)a; T.rep[nr].b = (unsigned char)b;
    T.rep[nr].c = (unsigned char)c; T.rep[nr].t = 3; nr++;
  }
  T.n3 = nr;
  // quadratic multisets a<=b
  for (int a = 0; a < 16; a++) for (int b = a; b < 16; b++) {
    const int key = (a << 4) | b;
    int aa = (a + 8) & 15, bb = (b + 8) & 15;
    if (aa > bb) { int t = aa; aa = bb; bb = t; }
    const int key2 = (aa << 4) | bb;
    if (key2 < key) continue;
    for (int h = 0; h < 2; h++) {
      const int kk = h ? key2 : key;
      if (!used2[kk]) {
        used2[kk] = true;
        const int f = (nr >> 3) * 16 + h * 8 + (nr & 7);
        T.slotmono[f].a = (unsigned char)(kk >> 4);
        T.slotmono[f].b = (unsigned char)(kk & 15);
        T.slotmono[f].c = 0;
        T.slotmono[f].t = 2;
      }
    }
    T.rep[nr].a = (unsigned char)a; T.rep[nr].b = (unsigned char)b;
    T.rep[nr].c = 0; T.rep[nr].t = 2; nr++;
  }
  T.n2 = nr;
  // linear: reps 0..7 (orbit {a, a+8})
  for (int a = 0; a < 8; a++) {
    for (int h = 0; h < 2; h++) {
      const int f = (nr >> 3) * 16 + h * 8 + (nr & 7);
      T.slotmono[f].a = (unsigned char)(h ? a + 8 : a);
      T.slotmono[f].b = 0; T.slotmono[f].c = 0; T.slotmono[f].t = 1;
    }
    T.rep[nr].a = (unsigned char)a; T.rep[nr].b = 0; T.rep[nr].c = 0;
    T.rep[nr].t = 1; nr++;
  }
  T.n1 = nr;
  return T;
}

constexpr Tables8 TT8 = build_tables8();
static_assert(TT8.n3 == 408, "cubic rep count");
static_assert(TT8.n2 == 480, "quad rep count");
static_assert(TT8.n1 == 488, "linear rep count == 61 chunks * 8");

__device__ const Tables8 g_T8 = build_tables8();   // runtime copy for prep kernel

// dims
#define BN 5888
#define CN 128
#define EN 10
#define NCHUNK 61          // 488 reps / 8; K = 976
#define NPATH 32           // 23 + 4 + 1 padded

DI u16 f2bf(float f) { union { __bf16 h; u16 s; } u; u.h = (__bf16)f; return u.s; }
DI float bf2f(u16 v) { union { u32 u; float f; } w; w.u = ((u32)v) << 16; return w.f; }

// ------------------------------------------------------------------
// prep kernel: ONE dispatch, no memset, no atomics.  One thread per
// packed-fragment u16: gathers its monomial's <=6 distinct U-index
// permutations, sums, converts to bf16, writes coalesced.
// ------------------------------------------------------------------
#define PREP_THREADS (NCHUNK * 64 * 8)     // 31232 = 122 * 256

__global__ void prep_kernel(const float* __restrict__ U3, const float* __restrict__ U2,
                            const float* __restrict__ U1, u16* __restrict__ Sfrag16) {
  const int tid = blockIdx.x * 256 + threadIdx.x;
  if (tid >= PREP_THREADS) return;
  const int j = tid & 7, l = (tid >> 3) & 63, c = tid >> 9;
  const int path = l & 31, h = l >> 5;
  const RepT m = g_T8.slotmono[c * 16 + h * 8 + j];
  float v = 0.f;
  if (m.t == 3 && path < 23) {
    const int a = m.a, b = m.b, d = m.c;
    v = U3[((a * 16 + b) * 16 + d) * 23 + path];
    if (a == b && b == d) {
      // single distinct permutation
    } else if (a == b) {            // (a,a,d): +ada, +daa
      v += U3[((a * 16 + d) * 16 + a) * 23 + path]
         + U3[((d * 16 + a) * 16 + a) * 23 + path];
    } else if (b == d) {            // (a,b,b): +bab, +bba
      v += U3[((b * 16 + a) * 16 + b) * 23 + path]
         + U3[((b * 16 + b) * 16 + a) * 23 + path];
    } else {                        // all distinct: 6 perms
      v += U3[((a * 16 + d) * 16 + b) * 23 + path]
         + U3[((b * 16 + a) * 16 + d) * 23 + path]
         + U3[((b * 16 + d) * 16 + a) * 23 + path]
         + U3[((d * 16 + a) * 16 + b) * 23 + path]
         + U3[((d * 16 + b) * 16 + a) * 23 + path];
    }
  } else if (m.t == 2 && path >= 23 && path < 27) {
    const int k = path - 23, a = m.a, b = m.b;
    v = U2[(a * 16 + b) * 4 + k];
    if (a != b) v += U2[(b * 16 + a) * 4 + k];
  } else if (m.t == 1 && path == 27) {
    v = U1[m.a];
  }
  Sfrag16[tid] = f2bf(v);
}

// ------------------------------------------------------------------
// main kernel (32x32x16 MFMA): wave covers 32 pairs x 32 paths with ONE
// A-tile ds_read per K-chunk.
// ------------------------------------------------------------------
template<int R>
DI float featf(const float* xr) {
  constexpr RepT rp = TT8.rep[R];
  if constexpr (rp.t == 3) return xr[rp.a] * xr[rp.b] * xr[rp.c];
  else if constexpr (rp.t == 2) return xr[rp.a] * xr[rp.b];
  else if constexpr (rp.t == 1) return xr[rp.a];
  else return 0.f;
}

template<int C>
DI bf16x8 make_B(const float* xr) {
  bf16x8 r;
  r[0] = (__bf16)featf<C * 8 + 0>(xr);
  r[1] = (__bf16)featf<C * 8 + 1>(xr);
  r[2] = (__bf16)featf<C * 8 + 2>(xr);
  r[3] = (__bf16)featf<C * 8 + 3>(xr);
  r[4] = (__bf16)featf<C * 8 + 4>(xr);
  r[5] = (__bf16)featf<C * 8 + 5>(xr);
  r[6] = (__bf16)featf<C * 8 + 6>(xr);
  r[7] = (__bf16)featf<C * 8 + 7>(xr);
  return r;
}

// A: path = lane&31, k = (lane>>5)*8 + j.  B: pair = lane&31, same k.
// ds_read address = single lane pointer + compile-time immediate.
template<int C>
DI void chunk_step(const uint4* sfl, const float* xr, f32x16& acc) {
  const bf16x8 B = make_B<C>(xr);
  const bf16x8 A = *reinterpret_cast<const bf16x8*>(sfl + C * 64);
  acc = __builtin_amdgcn_mfma_f32_32x32x16_bf16(A, B, acc, 0, 0, 0);
}

// sched_barrier(0) between chunks: the backend pins this kernel's register
// budget at the 64-total tier no matter what launch-bounds/waves-per-eu say
// (rounds 3/8/9: VGPR_Count=64, ~13 MB scratch writes).  One chunk's live
// set (~44 regs incl. 16-AGPR acc) fits the budget; it's the scheduler's
// cross-chunk hoisting of A-loads/B-builds that overflows it.  Cap the
// lookahead; latency hiding comes from 16 waves/CU TLP instead.
template<int... Cs>
DI void all_chunks(std::integer_sequence<int, Cs...>, const uint4* sfl,
                   const float* xr, f32x16& acc) {
  ((chunk_step<Cs>(sfl, xr, acc), __builtin_amdgcn_sched_barrier(0)), ...);
}

// xr[v] = x[pair][(v + 8h) & 15] via float4-group rotation at address level
DI void load_xr(const float* __restrict__ x, int pair, int h, float* xr) {
  const float* base = x + pair * 16;
#pragma unroll
  for (int u = 0; u < 4; u++) {
    const int g = (u + 2 * h) & 3;
    const float4 v = *(const float4*)(base + g * 4);
    xr[u * 4 + 0] = v.x;
    xr[u * 4 + 1] = v.y;
    xr[u * 4 + 2] = v.z;
    xr[u * 4 + 3] = v.w;
  }
}

// 512-thread blocks: LDS = 61 KB sfrag + 16 KB wbl = 77 KB -> 2 blocks/CU
// = 16 waves/CU (round 9: 2 blocks/CU beat 1 block/CU by 40 us).
__global__ __launch_bounds__(512, 4) void main_kernel(
    const float* __restrict__ x, const float* __restrict__ y,
    const float* __restrict__ w3, const float* __restrict__ w2, const float* __restrict__ w1,
    const uint4* __restrict__ Sfrag, float* __restrict__ out)
{
  __shared__ uint4 sfrag[NCHUNK * 64];         // 61 KB: S in A-frag order (straight copy)
  __shared__ u16  wbl[2 * 32 * 128];           // 16 KB: WB[bb][path][c] bf16
  const int tid = threadIdx.x;

  // stage S: straight uint4 copy (prep already packed bf16 fragments)
  for (int idx = tid; idx < NCHUNK * 64; idx += 512) sfrag[idx] = Sfrag[idx];

  // per-block WB = y @ concat(w3,w2,w1): block covers 2 consecutive b's.
  // thread t -> bb = t>>8, p = (t>>3)&31, c-chunk = (t&7)*16 : exactly 512.
  // Coalesced w-reads ONCE per block (round 5's per-lane inline version
  // thrashed L2 -> 990 MB fetch; never again).
  const int b0 = blockIdx.x * 2;
  {
    const int bb = tid >> 8;
    const int p  = (tid >> 3) & 31;
    const int c0 = (tid & 7) * 16;
    float yv[EN];
#pragma unroll
    for (int e = 0; e < EN; e++) yv[e] = y[(b0 + bb) * EN + e];
    float acc[16];
#pragma unroll
    for (int m = 0; m < 16; m++) acc[m] = 0.f;
    const float* wsrc = nullptr; int stride = 0;
    if (p < 23)       { wsrc = w3 + p * 128;        stride = 23 * 128; }
    else if (p < 27)  { wsrc = w2 + (p - 23) * 128; stride = 4 * 128; }
    else if (p == 27) { wsrc = w1;                  stride = 128; }
    if (wsrc) {
      for (int e = 0; e < EN; e++) {
        const float* src = wsrc + e * stride + c0;
        const float4 v0 = *(const float4*)(src);
        const float4 v1 = *(const float4*)(src + 4);
        const float4 v2 = *(const float4*)(src + 8);
        const float4 v3 = *(const float4*)(src + 12);
        const float vv[16] = {v0.x, v0.y, v0.z, v0.w, v1.x, v1.y, v1.z, v1.w,
                              v2.x, v2.y, v2.z, v2.w, v3.x, v3.y, v3.z, v3.w};
#pragma unroll
        for (int d = 0; d < 16; d++) acc[d] += yv[e] * vv[d];
      }
    }
#pragma unroll
    for (int m = 0; m < 16; m++) wbl[bb * 4096 + p * 128 + c0 + m] = f2bf(acc[m]);
  }
  __syncthreads();

  // wave handles 32 pairs; block = 8 waves * 32 = 256 pairs = 2 b's exactly
  const int wv = tid >> 6, lane = tid & 63;
  const int h = lane >> 5, col = lane & 31;
  const int pair0 = blockIdx.x * 256 + wv * 32 + col;

  float xr[16];
  load_xr(x, pair0, h, xr);

  const uint4* sfl = sfrag + lane;
  f32x16 acc = {};
  all_chunks(std::make_integer_sequence<int, NCHUNK>{}, sfl, xr, acc);

  // epilogue: out[pair] = sum_p D[p][pair] * WB[b][p][c].
  // D layout (32x32): col = lane&31 = pair, row = (reg&3)+8*(reg>>2)+4*h.
  const int bbw = wv >> 2;                 // waves 0-3 -> b0, 4-7 -> b0+1
  const int cc  = (wv & 3) * 32 + col;     // channel = pair0 % 128
  float p0 = 0.f;
#pragma unroll
  for (int rg = 0; rg < 16; rg++) {
    const int p = (rg & 3) + 8 * (rg >> 2) + 4 * h;
    p0 += acc[rg] * bf2f(wbl[bbw * 4096 + p * 128 + cc]);
  }
  p0 += __shfl_xor(p0, 32);                // combine the two K-halves
  if (h == 0) out[pair0] = p0;
}

// ------------------------------------------------------------------
extern "C" void kernel_launch(void* const* d_in, const int* in_sizes, int n_in,
                              void* d_out, int out_size, void* d_ws, size_t ws_size,
                              hipStream_t stream) {
  const float* x  = (const float*)d_in[0];
  const float* y  = (const float*)d_in[1];
  const float* U3 = (const float*)d_in[2];
  const float* U2 = (const float*)d_in[3];
  const float* U1 = (const float*)d_in[4];
  const float* w3 = (const float*)d_in[5];
  const float* w2 = (const float*)d_in[6];
  const float* w1 = (const float*)d_in[7];
  u16*   Sfrag16 = (u16*)d_ws;
  float* out     = (float*)d_out;

  hipLaunchKernelGGL(prep_kernel, dim3((PREP_THREADS + 255) / 256), dim3(256), 0, stream,
                     U3, U2, U1, Sfrag16);
  hipLaunchKernelGGL(main_kernel, dim3(2944), dim3(512), 0, stream,
                     x, y, w3, w2, w1, (const uint4*)d_ws, out);
}

// Round 11
// 179.110 us; speedup vs baseline: 6.1616x; 6.1616x over previous
//
#include <hip/hip_runtime.h>
#include <utility>

using u16 = unsigned short;
using u32 = unsigned int;

typedef float  f32x4  __attribute__((ext_vector_type(4)));
typedef __bf16 bf16x8 __attribute__((ext_vector_type(8)));

#define DI __device__ __forceinline__

// ------------------------------------------------------------------
// Monomial basis under the +4 rotation group (for 16x16x32 MFMA).
// Monomials over x[0..15]: cubic (816), quadratic (136), linear (16).
// Group action: rotation by +4q mod 16 (q=0..3).  Cubic orbits all size
// 4 -> 204 reps; quad: 32 size-4 orbits + 8 size-2 ({a,a+8}) -> 36 reps
// (8 dup slots stay null); linear -> 4 reps.  204+36+4 = 244, padded to
// 248 = 31 chunks * 8.
// Feature slot f = chunk*32 + q*8 + j  <->  rep r = chunk*8 + j,
// monomial = rot_{4q}(rep[r]).  Lane quad q = lane>>4 holds x rotated by
// 4q at the address level, so all lanes run identical compile-time code.
// ------------------------------------------------------------------
struct RepT { unsigned char a, b, c, t; };   // t: 3=cubic 2=quad 1=linear 0=null
struct Tables4 {
  RepT rep[248];        // compile-time rep list for feature templates
  RepT slotmono[992];   // per feature-slot: SORTED monomial (prep gather); t=0 if null/dup
  int n3, n2, n1;
};

constexpr int csort3key(int w, int x, int i) {
  int a = w, b = x, c = i, t = 0;
  if (a > b) { t = a; a = b; b = t; }
  if (b > c) { t = b; b = c; c = t; }
  if (a > b) { t = a; a = b; b = t; }
  return (a << 8) | (b << 4) | c;
}

constexpr Tables4 build_tables4() {
  Tables4 T = {};
  bool used3[4096] = {};
  bool used2[256] = {};
  int nr = 0;
  // cubic multisets a<=b<=c, canonical = lex-min over the 4 rotations
  for (int a = 0; a < 16; a++) for (int b = a; b < 16; b++) for (int c = b; c < 16; c++) {
    const int key = (a << 8) | (b << 4) | c;
    bool canon = true;
    for (int q = 1; q < 4; q++)
      if (csort3key((a + 4 * q) & 15, (b + 4 * q) & 15, (c + 4 * q) & 15) < key) canon = false;
    if (!canon) continue;
    for (int q = 0; q < 4; q++) {
      const int kk = csort3key((a + 4 * q) & 15, (b + 4 * q) & 15, (c + 4 * q) & 15);
      if (!used3[kk]) {
        used3[kk] = true;
        const int f = (nr >> 3) * 32 + q * 8 + (nr & 7);
        T.slotmono[f].a = (unsigned char)(kk >> 8);
        T.slotmono[f].b = (unsigned char)((kk >> 4) & 15);
        T.slotmono[f].c = (unsigned char)(kk & 15);
        T.slotmono[f].t = 3;
      }
    }
    T.rep[nr].a = (unsigned char)a; T.rep[nr].b = (unsigned char)b;
    T.rep[nr].c = (unsigned char)c; T.rep[nr].t = 3; nr++;
  }
  T.n3 = nr;
  // quadratic multisets a<=b
  for (int a = 0; a < 16; a++) for (int b = a; b < 16; b++) {
    const int key = (a << 4) | b;
    bool canon = true;
    for (int q = 1; q < 4; q++) {
      int aa = (a + 4 * q) & 15, bb = (b + 4 * q) & 15;
      if (aa > bb) { int t = aa; aa = bb; bb = t; }
      if (((aa << 4) | bb) < key) canon = false;
    }
    if (!canon) continue;
    for (int q = 0; q < 4; q++) {
      int aa = (a + 4 * q) & 15, bb = (b + 4 * q) & 15;
      if (aa > bb) { int t = aa; aa = bb; bb = t; }
      const int kk = (aa << 4) | bb;
      if (!used2[kk]) {
        used2[kk] = true;
        const int f = (nr >> 3) * 32 + q * 8 + (nr & 7);
        T.slotmono[f].a = (unsigned char)(kk >> 4);
        T.slotmono[f].b = (unsigned char)(kk & 15);
        T.slotmono[f].c = 0;
        T.slotmono[f].t = 2;
      }
    }
    T.rep[nr].a = (unsigned char)a; T.rep[nr].b = (unsigned char)b;
    T.rep[nr].c = 0; T.rep[nr].t = 2; nr++;
  }
  T.n2 = nr;
  // linear: reps 0..3, orbit {a, a+4, a+8, a+12}
  for (int a = 0; a < 4; a++) {
    for (int q = 0; q < 4; q++) {
      const int f = (nr >> 3) * 32 + q * 8 + (nr & 7);
      T.slotmono[f].a = (unsigned char)((a + 4 * q) & 15);
      T.slotmono[f].b = 0; T.slotmono[f].c = 0; T.slotmono[f].t = 1;
    }
    T.rep[nr].a = (unsigned char)a; T.rep[nr].b = 0; T.rep[nr].c = 0;
    T.rep[nr].t = 1; nr++;
  }
  T.n1 = nr;
  for (; nr < 248; nr++) { T.rep[nr].a = 0; T.rep[nr].b = 0; T.rep[nr].c = 0; T.rep[nr].t = 0; }
  return T;
}

constexpr Tables4 TT4 = build_tables4();
static_assert(TT4.n3 == 204, "cubic rep count");
static_assert(TT4.n2 == 240, "quad rep count");
static_assert(TT4.n1 == 244, "linear rep count");

__device__ const Tables4 g_T4 = build_tables4();   // runtime copy for prep kernel

// dims
#define BN 5888
#define CN 128
#define EN 10
#define NCHUNK 31          // 248 reps / 8; K = 992
#define NPATH 32           // 23 + 4 + 1 padded

DI u16 f2bf(float f) { union { __bf16 h; u16 s; } u; u.h = (__bf16)f; return u.s; }
DI float bf2f(u16 v) { union { u32 u; float f; } w; w.u = ((u32)v) << 16; return w.f; }

// ------------------------------------------------------------------
// prep kernel: ONE dispatch, no memset, no atomics.  One thread per
// packed-fragment u16: gathers its monomial's <=6 distinct U-index
// permutations, sums, converts to bf16, writes coalesced.
// Fragment layout (matches main's staging copy exactly):
// uint4 idx = cp*64 + l; cp = chunk*2 + P; lane l: path = P*16 + (l&15),
// q = l>>4; u16 j in [0,8): feature slot = chunk*32 + q*8 + j.
// ------------------------------------------------------------------
#define PREP_THREADS (NCHUNK * 2 * 64 * 8)     // 31744 u16 = 62 KB

__global__ void prep_kernel(const float* __restrict__ U3, const float* __restrict__ U2,
                            const float* __restrict__ U1, u16* __restrict__ Sfrag16) {
  const int tid = blockIdx.x * 256 + threadIdx.x;
  if (tid >= PREP_THREADS) return;
  const int j = tid & 7, l = (tid >> 3) & 63, cp = tid >> 9;
  const int chunk = cp >> 1, P = cp & 1;
  const int path = P * 16 + (l & 15), q = l >> 4;
  const RepT m = g_T4.slotmono[chunk * 32 + q * 8 + j];
  float v = 0.f;
  if (m.t == 3 && path < 23) {
    const int a = m.a, b = m.b, d = m.c;
    v = U3[((a * 16 + b) * 16 + d) * 23 + path];
    if (a == b && b == d) {
      // single distinct permutation
    } else if (a == b) {            // (a,a,d): +ada, +daa
      v += U3[((a * 16 + d) * 16 + a) * 23 + path]
         + U3[((d * 16 + a) * 16 + a) * 23 + path];
    } else if (b == d) {            // (a,b,b): +bab, +bba
      v += U3[((b * 16 + a) * 16 + b) * 23 + path]
         + U3[((b * 16 + b) * 16 + a) * 23 + path];
    } else {                        // all distinct: 6 perms
      v += U3[((a * 16 + d) * 16 + b) * 23 + path]
         + U3[((b * 16 + a) * 16 + d) * 23 + path]
         + U3[((b * 16 + d) * 16 + a) * 23 + path]
         + U3[((d * 16 + a) * 16 + b) * 23 + path]
         + U3[((d * 16 + b) * 16 + a) * 23 + path];
    }
  } else if (m.t == 2 && path >= 23 && path < 27) {
    const int k = path - 23, a = m.a, b = m.b;
    v = U2[(a * 16 + b) * 4 + k];
    if (a != b) v += U2[(b * 16 + a) * 4 + k];
  } else if (m.t == 1 && path == 27) {
    v = U1[m.a];
  }
  Sfrag16[tid] = f2bf(v);
}

// ------------------------------------------------------------------
// main kernel (16x16x32 MFMA): the only structure measured spill-free
// under the backend's immovable 64-VGPR cap (rounds 4/6: VGPR 44-48,
// WRITE = output only).  NO sched_barrier (round 10: 8x regression).
// ------------------------------------------------------------------
template<int R>
DI float featf(const float* xr) {
  constexpr RepT rp = TT4.rep[R];
  if constexpr (rp.t == 3) return xr[rp.a] * xr[rp.b] * xr[rp.c];
  else if constexpr (rp.t == 2) return xr[rp.a] * xr[rp.b];
  else if constexpr (rp.t == 1) return xr[rp.a];
  else return 0.f;
}

template<int C>
DI bf16x8 make_B(const float* xr) {
  bf16x8 r;
  r[0] = (__bf16)featf<C * 8 + 0>(xr);
  r[1] = (__bf16)featf<C * 8 + 1>(xr);
  r[2] = (__bf16)featf<C * 8 + 2>(xr);
  r[3] = (__bf16)featf<C * 8 + 3>(xr);
  r[4] = (__bf16)featf<C * 8 + 4>(xr);
  r[5] = (__bf16)featf<C * 8 + 5>(xr);
  r[6] = (__bf16)featf<C * 8 + 6>(xr);
  r[7] = (__bf16)featf<C * 8 + 7>(xr);
  return r;
}

// A: path/k fragment from LDS (2 path-tiles); B: 8 features of this pair.
// B built before the A-loads to keep A's live range ds_read -> MFMA.
template<int C>
DI void chunk_step(const uint4* sfl, const float* xr, f32x4& a0, f32x4& a1) {
  const bf16x8 B = make_B<C>(xr);
  const bf16x8 A0 = *reinterpret_cast<const bf16x8*>(sfl + (C * 2 + 0) * 64);
  const bf16x8 A1 = *reinterpret_cast<const bf16x8*>(sfl + (C * 2 + 1) * 64);
  a0 = __builtin_amdgcn_mfma_f32_16x16x32_bf16(A0, B, a0, 0, 0, 0);
  a1 = __builtin_amdgcn_mfma_f32_16x16x32_bf16(A1, B, a1, 0, 0, 0);
}

template<int... Cs>
DI void all_chunks(std::integer_sequence<int, Cs...>, const uint4* sfl,
                   const float* xr, f32x4& a0, f32x4& a1) {
  (chunk_step<Cs>(sfl, xr, a0, a1), ...);
}

// xr[v] = x[pair][(v + 4q) & 15] via float4-group rotation at address level
DI void load_xr(const float* __restrict__ x, int pair, int q, float* xr) {
  const float* base = x + pair * 16;
#pragma unroll
  for (int u = 0; u < 4; u++) {
    const int g = (u + q) & 3;
    const float4 v = *(const float4*)(base + g * 4);
    xr[u * 4 + 0] = v.x;
    xr[u * 4 + 1] = v.y;
    xr[u * 4 + 2] = v.z;
    xr[u * 4 + 3] = v.w;
  }
}

// 512-thread blocks: LDS = 62 KB sfrag + 8 KB wbl = 70 KB -> 2 blocks/CU
// = 16 waves/CU (round 9: 2 blocks/CU beat 1 by 40 us on identical code).
// Block = 8 waves * 16 pairs = 128 pairs = exactly 1 node.
__global__ __launch_bounds__(512) void main_kernel(
    const float* __restrict__ x, const float* __restrict__ y,
    const float* __restrict__ w3, const float* __restrict__ w2, const float* __restrict__ w1,
    const uint4* __restrict__ Sfrag, float* __restrict__ out)
{
  __shared__ uint4 sfrag[NCHUNK * 2 * 64];     // 62 KB: S in A-frag order (straight copy)
  __shared__ u16  wbl[32 * 128];               // 8 KB: WB[path][c] bf16, this node
  const int tid = threadIdx.x;

  // stage S: straight uint4 copy (prep already packed bf16 fragments)
  for (int idx = tid; idx < NCHUNK * 2 * 64; idx += 512) sfrag[idx] = Sfrag[idx];

  // per-block WB = y[b] @ concat(w3,w2,w1) for this node.
  // thread t -> p = t>>4, c-octet = (t&15)*8 : exactly 512.
  // Coalesced w-reads ONCE per block (round 5: per-lane inline w-loads
  // thrashed L2 -> 990 MB fetch; never again).
  const int bnode = blockIdx.x;
  {
    const int p  = tid >> 4;
    const int c0 = (tid & 15) * 8;
    float yv[EN];
#pragma unroll
    for (int e = 0; e < EN; e++) yv[e] = y[bnode * EN + e];
    float acc[8];
#pragma unroll
    for (int m = 0; m < 8; m++) acc[m] = 0.f;
    const float* wsrc = nullptr; int stride = 0;
    if (p < 23)       { wsrc = w3 + p * 128;        stride = 23 * 128; }
    else if (p < 27)  { wsrc = w2 + (p - 23) * 128; stride = 4 * 128; }
    else if (p == 27) { wsrc = w1;                  stride = 128; }
    if (wsrc) {
      for (int e = 0; e < EN; e++) {
        const float* src = wsrc + e * stride + c0;
        const float4 v0 = *(const float4*)(src);
        const float4 v1 = *(const float4*)(src + 4);
        acc[0] += yv[e] * v0.x; acc[1] += yv[e] * v0.y;
        acc[2] += yv[e] * v0.z; acc[3] += yv[e] * v0.w;
        acc[4] += yv[e] * v1.x; acc[5] += yv[e] * v1.y;
        acc[6] += yv[e] * v1.z; acc[7] += yv[e] * v1.w;
      }
    }
#pragma unroll
    for (int m = 0; m < 8; m++) wbl[p * 128 + c0 + m] = f2bf(acc[m]);
  }
  __syncthreads();

  // wave handles 16 pairs (1 pair-tile); block = 128 pairs = 1 node
  const int wv = tid >> 6, lane = tid & 63;
  const int q = lane >> 4, n = lane & 15;
  const int pair0 = bnode * 128 + wv * 16 + n;

  float xr[16];
  load_xr(x, pair0, q, xr);

  const uint4* sfl = sfrag + lane;
  f32x4 a0 = {0.f, 0.f, 0.f, 0.f};
  f32x4 a1 = a0;
  all_chunks(std::make_integer_sequence<int, NCHUNK>{}, sfl, xr, a0, a1);

  // epilogue: out[pair] = sum_p D[p][pair] * WB[p][c], reduce over quads.
  // D layout (16x16x32): col = lane&15 = pair, row = q*4+rg = path.
  const int cc = wv * 16 + n;              // channel = pair0 % 128
  float p0 = 0.f;
#pragma unroll
  for (int rg = 0; rg < 4; rg++) {
    p0 += a0[rg] * bf2f(wbl[(q * 4 + rg) * 128 + cc]);
    p0 += a1[rg] * bf2f(wbl[(16 + q * 4 + rg) * 128 + cc]);
  }
  p0 += __shfl_xor(p0, 16);
  p0 += __shfl_xor(p0, 32);
  if (q == 0) out[pair0] = p0;
}

// ------------------------------------------------------------------
extern "C" void kernel_launch(void* const* d_in, const int* in_sizes, int n_in,
                              void* d_out, int out_size, void* d_ws, size_t ws_size,
                              hipStream_t stream) {
  const float* x  = (const float*)d_in[0];
  const float* y  = (const float*)d_in[1];
  const float* U3 = (const float*)d_in[2];
  const float* U2 = (const float*)d_in[3];
  const float* U1 = (const float*)d_in[4];
  const float* w3 = (const float*)d_in[5];
  const float* w2 = (const float*)d_in[6];
  const float* w1 = (const float*)d_in[7];
  u16*   Sfrag16 = (u16*)d_ws;
  float* out     = (float*)d_out;

  hipLaunchKernelGGL(prep_kernel, dim3((PREP_THREADS + 255) / 256), dim3(256), 0, stream,
                     U3, U2, U1, Sfrag16);
  hipLaunchKernelGGL(main_kernel, dim3(BN), dim3(512), 0, stream,
                     x, y, w3, w2, w1, (const uint4*)d_ws, out);
}